// Round 1
// baseline (1710.597 us; speedup 1.0000x reference)
//
#include <hip/hip_runtime.h>

#define NJ 128   // images
#define NI 128   // captions
#define NR 36    // regions
#define NW 32    // words
#define ND 1024  // feature dim

#define LAM_SM 9.0f
#define LAM_LSE 6.0f
#define MARGIN 0.2f
#define EPSF 1e-8f

#define G_SZ (NJ * NR * NR)
#define W1_SZ (NI * NW)

__device__ __forceinline__ float dot4(float4 a, float4 b) {
    return a.x * b.x + a.y * b.y + a.z * b.z + a.w * b.w;
}

// ---------------- Gram matrices G[j] = im[j] @ im[j]^T (36x36) ----------------
__global__ __launch_bounds__(256) void gram_kernel(const float* __restrict__ im,
                                                   float* __restrict__ G) {
    const int j = blockIdx.x;
    __shared__ float sIm[NR][132];
    const float* imj = im + (size_t)j * NR * ND;
    const int tid = threadIdx.x;
    float acc[6] = {0.f, 0.f, 0.f, 0.f, 0.f, 0.f};
    for (int d0 = 0; d0 < ND; d0 += 128) {
        __syncthreads();
        for (int q = tid; q < NR * 32; q += 256) {
            int r = q >> 5, c4 = q & 31;
            *(float4*)(&sIm[r][c4 * 4]) = *(const float4*)(imj + r * ND + d0 + c4 * 4);
        }
        __syncthreads();
        for (int k = 0; k < 6; ++k) {
            int e = tid + k * 256;
            if (e < NR * NR) {
                int a = e / NR, b = e % NR;
                const float4* ra = (const float4*)(&sIm[a][0]);
                const float4* rb = (const float4*)(&sIm[b][0]);
                float ssum = 0.f;
                for (int c4 = 0; c4 < 32; ++c4) ssum += dot4(ra[c4], rb[c4]);
                acc[k] += ssum;
            }
        }
    }
    for (int k = 0; k < 6; ++k) {
        int e = tid + k * 256;
        if (e < NR * NR) G[(size_t)j * (NR * NR) + e] = acc[k];
    }
}

// ---------------- word norms w1[i][w] = ||s[i,w,:]|| ----------------
__global__ __launch_bounds__(256) void wnorm_kernel(const float* __restrict__ s,
                                                    float* __restrict__ w1) {
    const int i = blockIdx.x;
    const int tid = threadIdx.x;
    const int w = tid >> 3;    // 0..31
    const int part = tid & 7;  // 0..7
    const float* sw = s + ((size_t)i * NW + w) * ND;
    float acc = 0.f;
    for (int k = 0; k < 32; ++k) {
        int c = (part + k * 8) * 4;
        float4 v = *(const float4*)(sw + c);
        acc += v.x * v.x + v.y * v.y + v.z * v.z + v.w * v.w;
    }
    acc += __shfl_xor(acc, 1);
    acc += __shfl_xor(acc, 2);
    acc += __shfl_xor(acc, 4);
    if (part == 0) w1[i * NW + w] = sqrtf(acc);
}

// ---------------- per-pair kernel: A0 GEMM + fused epilogue -> scores[j][i] ----------------
__global__ __launch_bounds__(256) void pair_kernel(const float* __restrict__ im,
                                                   const float* __restrict__ s,
                                                   const float* __restrict__ G,
                                                   const float* __restrict__ w1g,
                                                   float* __restrict__ scores) {
    const int i = blockIdx.x;  // caption
    const int j = blockIdx.y;  // image

    __shared__ float sIm[48][132];     // rows 36..47 zero pad
    __shared__ float sS[NW][132];
    __shared__ float A0[NR][33];       // raw dots
    __shared__ float attn[NR][33];     // softmax attention (column-wise over r)
    __shared__ float gG[NR][NR];
    __shared__ float tmpWR[NW][NR];    // t[w][r'] = sum_r attn[r][w] * G[r][r']
    __shared__ float nrm[NR];
    __shared__ float numv[NW];
    __shared__ float simv[NW];

    const int tid = threadIdx.x;
    const int tx = tid & 15;   // w-group
    const int ty = tid >> 4;   // r-group

    // zero the pad rows (written once, never overwritten)
    for (int q = tid; q < 12 * 132; q += 256) (&sIm[0][0])[36 * 132 + q] = 0.f;

    const float* imj = im + (size_t)j * NR * ND;
    const float* si = s + (size_t)i * NW * ND;

    const int r0 = ty, r1 = ty + 16, r2 = ty + 32;  // r2 real only for ty<4, else zero rows
    const int w0 = tx, w1i = tx + 16;

    float acc00 = 0.f, acc01 = 0.f, acc10 = 0.f, acc11 = 0.f, acc20 = 0.f, acc21 = 0.f;

    for (int d0 = 0; d0 < ND; d0 += 128) {
        __syncthreads();
        for (int q = tid; q < NR * 32; q += 256) {
            int r = q >> 5, c4 = q & 31;
            *(float4*)(&sIm[r][c4 * 4]) = *(const float4*)(imj + r * ND + d0 + c4 * 4);
        }
        for (int q = tid; q < NW * 32; q += 256) {
            int w = q >> 5, c4 = q & 31;
            *(float4*)(&sS[w][c4 * 4]) = *(const float4*)(si + w * ND + d0 + c4 * 4);
        }
        __syncthreads();
#pragma unroll 8
        for (int c4 = 0; c4 < 32; ++c4) {
            float4 b0 = *(const float4*)(&sS[w0][c4 * 4]);
            float4 b1 = *(const float4*)(&sS[w1i][c4 * 4]);
            float4 a0 = *(const float4*)(&sIm[r0][c4 * 4]);
            float4 a1 = *(const float4*)(&sIm[r1][c4 * 4]);
            float4 a2 = *(const float4*)(&sIm[r2][c4 * 4]);
            acc00 += dot4(a0, b0); acc01 += dot4(a0, b1);
            acc10 += dot4(a1, b0); acc11 += dot4(a1, b1);
            acc20 += dot4(a2, b0); acc21 += dot4(a2, b1);
        }
    }

    __syncthreads();
    A0[r0][w0] = acc00; A0[r0][w1i] = acc01;
    A0[r1][w0] = acc10; A0[r1][w1i] = acc11;
    if (ty < 4) { A0[r2][w0] = acc20; A0[r2][w1i] = acc21; }
    // stage Gram matrix while A0 settles
    for (int q = tid; q < NR * NR; q += 256) (&gG[0][0])[q] = G[(size_t)j * (NR * NR) + q];
    __syncthreads();

    // per-region L2 norm over words (after LeakyReLU)
    if (tid < NR) {
        float ssum = 0.f;
        for (int w = 0; w < NW; ++w) {
            float v = A0[tid][w];
            v = v > 0.f ? v : 0.1f * v;
            ssum += v * v;
        }
        nrm[tid] = sqrtf(ssum) + EPSF;
    }
    __syncthreads();

    // per-word softmax over regions + numerator
    if (tid < NW) {
        const int w = tid;
        float m = -1e30f;
        for (int r = 0; r < NR; ++r) {
            float v = A0[r][w];
            v = v > 0.f ? v : 0.1f * v;
            v = LAM_SM * v / nrm[r];
            attn[r][w] = v;
            m = fmaxf(m, v);
        }
        float ssum = 0.f;
        for (int r = 0; r < NR; ++r) {
            float e = expf(attn[r][w] - m);
            attn[r][w] = e;
            ssum += e;
        }
        float inv = 1.f / ssum;
        float nm = 0.f;
        for (int r = 0; r < NR; ++r) {
            float a = attn[r][w] * inv;
            attn[r][w] = a;
            nm += a * A0[r][w];
        }
        numv[w] = nm;
    }
    __syncthreads();

    // t[w][r'] = sum_r attn[r][w] * G[r][r']  (parallel over all 1152 entries)
    for (int e = tid; e < NW * NR; e += 256) {
        int w = e / NR, rp = e % NR;
        float t = 0.f;
        for (int r = 0; r < NR; ++r) t += attn[r][w] * gG[r][rp];
        (&tmpWR[0][0])[e] = t;
    }
    __syncthreads();

    // cosine sim per word, then logsumexp over words
    if (tid < NW) {
        const int w = tid;
        float q = 0.f;
        for (int rp = 0; rp < NR; ++rp) q += tmpWR[w][rp] * attn[rp][w];
        float w2 = sqrtf(fmaxf(q, 0.f));
        float denom = fmaxf(w1g[i * NW + w] * w2, EPSF);
        simv[w] = numv[w] / denom;
    }
    __syncthreads();
    if (tid < NW) {
        float v = simv[tid];
        float m = v;
        for (int off = 16; off; off >>= 1) m = fmaxf(m, __shfl_xor(m, off));
        float e = expf(LAM_LSE * (v - m));
        float ssum = e;
        for (int off = 16; off; off >>= 1) ssum += __shfl_xor(ssum, off);
        if (tid == 0) scores[(size_t)j * NI + i] = m + logf(ssum) / LAM_LSE;
    }
}

// ---------------- final hinge loss over the 128x128 score matrix ----------------
__global__ __launch_bounds__(256) void loss_kernel(const float* __restrict__ scores,
                                                   float* __restrict__ out) {
    __shared__ float diag[NJ];
    __shared__ float part[256];
    const int tid = threadIdx.x;
    if (tid < NJ) diag[tid] = scores[tid * NI + tid];
    __syncthreads();
    float m = 0.f;  // clip(...,0) + zeroed diagonal => max starts at 0
    if (tid < 128) {
        const int a = tid;  // row (image axis)
        const float da = diag[a];
        for (int b = 0; b < NI; ++b) {
            if (b == a) continue;
            float c = MARGIN + scores[a * NI + b] - da;
            m = fmaxf(m, c);
        }
    } else {
        const int b = tid - 128;  // column (caption axis)
        const float db = diag[b];
        for (int a = 0; a < NJ; ++a) {
            if (a == b) continue;
            float c = MARGIN + scores[a * NI + b] - db;
            m = fmaxf(m, c);
        }
    }
    part[tid] = m;
    __syncthreads();
    for (int st = 128; st > 0; st >>= 1) {
        if (tid < st) part[tid] += part[tid + st];
        __syncthreads();
    }
    if (tid == 0) out[0] = part[0];
}

extern "C" void kernel_launch(void* const* d_in, const int* in_sizes, int n_in,
                              void* d_out, int out_size, void* d_ws, size_t ws_size,
                              hipStream_t stream) {
    const float* im = (const float*)d_in[0];
    const float* s = (const float*)d_in[1];
    float* G = (float*)d_ws;
    float* w1 = G + G_SZ;
    float* scores = w1 + W1_SZ;

    gram_kernel<<<dim3(NJ), dim3(256), 0, stream>>>(im, G);
    wnorm_kernel<<<dim3(NI), dim3(256), 0, stream>>>(s, w1);
    pair_kernel<<<dim3(NI, NJ), dim3(256), 0, stream>>>(im, s, G, w1, scores);
    loss_kernel<<<dim3(1), dim3(256), 0, stream>>>(scores, (float*)d_out);
}

// Round 2
// 240.890 us; speedup vs baseline: 7.1012x; 7.1012x over previous
//
#include <hip/hip_runtime.h>

#define NJ 128   // images
#define NI 128   // captions
#define NR 36    // regions
#define NW 32    // words
#define ND 1024  // feature dim

#define LAM_SM 9.0f
#define LAM_LSE 6.0f
#define MARGIN 0.2f
#define EPSF 1e-8f

#define BK 64

typedef __attribute__((ext_vector_type(8))) short s16x8;
typedef __attribute__((ext_vector_type(4))) float f32x4;

#define IM_ELEMS (NJ * NR * ND)   // 4718592
#define S_ELEMS  (NI * NW * ND)   // 4194304
#define G_SZ (NJ * NR * NR)
#define W1_SZ (NI * NW)

__device__ __forceinline__ float dot4(float4 a, float4 b) {
    return a.x * b.x + a.y * b.y + a.z * b.z + a.w * b.w;
}

__device__ __forceinline__ unsigned short f2bf(float x) {
    unsigned u = __float_as_uint(x);
    return (unsigned short)((u + 0x7FFFu + ((u >> 16) & 1u)) >> 16);
}

// ---------------- f32 -> bf16 conversion ----------------
__global__ __launch_bounds__(256) void cvt_kernel(const float* __restrict__ src,
                                                  unsigned short* __restrict__ dst, int n4) {
    int idx = blockIdx.x * 256 + threadIdx.x;
    if (idx < n4) {
        float4 v = ((const float4*)src)[idx];
        ushort4 o;
        o.x = f2bf(v.x); o.y = f2bf(v.y); o.z = f2bf(v.z); o.w = f2bf(v.w);
        ((ushort4*)dst)[idx] = o;
    }
}

// ---------------- Gram matrices G[j] = im[j] @ im[j]^T (36x36, f32 exact) ----------------
__global__ __launch_bounds__(256) void gram_kernel(const float* __restrict__ im,
                                                   float* __restrict__ G) {
    const int j = blockIdx.x;
    __shared__ float sIm[NR][132];
    const float* imj = im + (size_t)j * NR * ND;
    const int tid = threadIdx.x;
    float acc[6] = {0.f, 0.f, 0.f, 0.f, 0.f, 0.f};
    for (int d0 = 0; d0 < ND; d0 += 128) {
        __syncthreads();
        for (int q = tid; q < NR * 32; q += 256) {
            int r = q >> 5, c4 = q & 31;
            *(float4*)(&sIm[r][c4 * 4]) = *(const float4*)(imj + r * ND + d0 + c4 * 4);
        }
        __syncthreads();
        for (int k = 0; k < 6; ++k) {
            int e = tid + k * 256;
            if (e < NR * NR) {
                int a = e / NR, b = e % NR;
                const float4* ra = (const float4*)(&sIm[a][0]);
                const float4* rb = (const float4*)(&sIm[b][0]);
                float ssum = 0.f;
                for (int c4 = 0; c4 < 32; ++c4) ssum += dot4(ra[c4], rb[c4]);
                acc[k] += ssum;
            }
        }
    }
    for (int k = 0; k < 6; ++k) {
        int e = tid + k * 256;
        if (e < NR * NR) G[(size_t)j * (NR * NR) + e] = acc[k];
    }
}

// ---------------- word norms w1[i][w] = ||s[i,w,:]|| (f32 exact) ----------------
__global__ __launch_bounds__(256) void wnorm_kernel(const float* __restrict__ s,
                                                    float* __restrict__ w1) {
    const int i = blockIdx.x;
    const int tid = threadIdx.x;
    const int w = tid >> 3;
    const int part = tid & 7;
    const float* sw = s + ((size_t)i * NW + w) * ND;
    float acc = 0.f;
    for (int k = 0; k < 32; ++k) {
        int c = (part + k * 8) * 4;
        float4 v = *(const float4*)(sw + c);
        acc += v.x * v.x + v.y * v.y + v.z * v.z + v.w * v.w;
    }
    acc += __shfl_xor(acc, 1);
    acc += __shfl_xor(acc, 2);
    acc += __shfl_xor(acc, 4);
    if (part == 0) w1[i * NW + w] = sqrtf(acc);
}

// ---------------- MFMA pair kernel: block = (image j) x (8 captions) ----------------
// GEMM: A (48x1024, rows 36..47 zero) x B^T (256 words x 1024) -> D (48x256)
// wave wv owns caption ig*8+wv (cols wv*32..wv*32+31), then full fused epilogue.
__global__ __launch_bounds__(512) void mfma_pair_kernel(const unsigned short* __restrict__ imh,
                                                        const unsigned short* __restrict__ sh,
                                                        const float* __restrict__ G,
                                                        const float* __restrict__ w1g,
                                                        float* __restrict__ scores) {
    const int ig = blockIdx.x;   // caption group of 8
    const int j = blockIdx.y;    // image
    const int tid = threadIdx.x;
    const int l = tid & 63, wv = tid >> 6;
    const int grp = l >> 4, lw = l & 15;

    // smem map: [0,6144) sA bf16 48x64 swz | [6144,38912) sB bf16 256x64 swz
    //           union [0,38016) attnS f32 [8][36][33]
    //           [38912,44096) gG f32 36x36 | [44096,45120) numS f32 [8][32]
    __shared__ __align__(16) char smem[45120];
    unsigned short* sA = (unsigned short*)smem;
    unsigned short* sB = (unsigned short*)(smem + 6144);
    float* attnS = (float*)smem;
    float* gG = (float*)(smem + 38912);
    float* numS = (float*)(smem + 44096);

    // stage Gram (exact f32), survives GEMM (separate region)
    for (int q = tid; q < NR * NR; q += 512) gG[q] = G[(size_t)j * (NR * NR) + q];

    f32x4 acc[3][2];
#pragma unroll
    for (int m = 0; m < 3; ++m)
#pragma unroll
        for (int n = 0; n < 2; ++n) acc[m][n] = (f32x4){0.f, 0.f, 0.f, 0.f};

    const size_t imBase = (size_t)j * NR * ND;
    const size_t sBase = (size_t)ig * 256 * ND;

    for (int k0 = 0; k0 < ND; k0 += BK) {
        __syncthreads();
        // stage A: 48 rows x 64 cols bf16, XOR-swizzled 16B chunks
        if (tid < 384) {
            int row = tid >> 3, c8 = tid & 7;
            int pc = c8 ^ (row & 7);
            int4 v = make_int4(0, 0, 0, 0);
            if (row < NR) v = *(const int4*)(imh + imBase + (size_t)row * ND + k0 + c8 * 8);
            *(int4*)(sA + row * 64 + pc * 8) = v;
        }
        // stage B: 256 rows x 64 cols
#pragma unroll
        for (int t = 0; t < 4; ++t) {
            int q = tid + t * 512;
            int row = q >> 3, c8 = q & 7;
            int pc = c8 ^ (row & 7);
            int4 v = *(const int4*)(sh + sBase + (size_t)row * ND + k0 + c8 * 8);
            *(int4*)(sB + row * 64 + pc * 8) = v;
        }
        __syncthreads();
#pragma unroll
        for (int ks = 0; ks < 2; ++ks) {
            const int ckc = ks * 4 + grp;  // k-chunk index (8 bf16 each), kc = ks*32+grp*8
            s16x8 a0, a1, a2, b0, b1;
            {
                int r = lw;
                a0 = *(const s16x8*)(sA + r * 64 + ((ckc ^ (r & 7)) << 3));
                r = 16 + lw;
                a1 = *(const s16x8*)(sA + r * 64 + ((ckc ^ (r & 7)) << 3));
                r = 32 + lw;
                a2 = *(const s16x8*)(sA + r * 64 + ((ckc ^ (r & 7)) << 3));
                int br = wv * 32 + lw;
                b0 = *(const s16x8*)(sB + br * 64 + ((ckc ^ (br & 7)) << 3));
                br = wv * 32 + 16 + lw;
                b1 = *(const s16x8*)(sB + br * 64 + ((ckc ^ (br & 7)) << 3));
            }
            acc[0][0] = __builtin_amdgcn_mfma_f32_16x16x32_bf16(a0, b0, acc[0][0], 0, 0, 0);
            acc[0][1] = __builtin_amdgcn_mfma_f32_16x16x32_bf16(a0, b1, acc[0][1], 0, 0, 0);
            acc[1][0] = __builtin_amdgcn_mfma_f32_16x16x32_bf16(a1, b0, acc[1][0], 0, 0, 0);
            acc[1][1] = __builtin_amdgcn_mfma_f32_16x16x32_bf16(a1, b1, acc[1][1], 0, 0, 0);
            acc[2][0] = __builtin_amdgcn_mfma_f32_16x16x32_bf16(a2, b0, acc[2][0], 0, 0, 0);
            acc[2][1] = __builtin_amdgcn_mfma_f32_16x16x32_bf16(a2, b1, acc[2][1], 0, 0, 0);
        }
    }
    __syncthreads();  // GEMM fully done; smem union becomes attnS

    // ---- fused per-wave epilogue: wave wv handles caption i ----
    const int i = ig * 8 + wv;
    // D element (m,n,reg): row r = m*16 + grp*4 + reg (region), col w = n*16 + lw (word)

    // 1) row L2-norms over words (after LeakyReLU): reduce across 16 lanes (lw)
    float nrmv[3][4];
#pragma unroll
    for (int m = 0; m < 3; ++m)
#pragma unroll
        for (int reg = 0; reg < 4; ++reg) {
            float a0 = acc[m][0][reg], a1 = acc[m][1][reg];
            float l0 = a0 > 0.f ? a0 : 0.1f * a0;
            float l1 = a1 > 0.f ? a1 : 0.1f * a1;
            float ssum = l0 * l0 + l1 * l1;
            ssum += __shfl_xor(ssum, 1);
            ssum += __shfl_xor(ssum, 2);
            ssum += __shfl_xor(ssum, 4);
            ssum += __shfl_xor(ssum, 8);
            nrmv[m][reg] = sqrtf(ssum) + EPSF;
        }

    // 2) logits, column-softmax over regions (reduce across grp: xor 16,32)
    float tt[3][2][4];
    float mx[2] = {-1e30f, -1e30f};
#pragma unroll
    for (int m = 0; m < 3; ++m)
#pragma unroll
        for (int n = 0; n < 2; ++n)
#pragma unroll
            for (int reg = 0; reg < 4; ++reg) {
                bool valid = (m < 2) || (grp == 0);  // rows >= 36 are pad
                float a = acc[m][n][reg];
                float lk = a > 0.f ? a : 0.1f * a;
                float t = LAM_SM * lk / nrmv[m][reg];
                tt[m][n][reg] = valid ? t : -1e30f;
                if (valid) mx[n] = fmaxf(mx[n], t);
            }
#pragma unroll
    for (int n = 0; n < 2; ++n) {
        mx[n] = fmaxf(mx[n], __shfl_xor(mx[n], 16));
        mx[n] = fmaxf(mx[n], __shfl_xor(mx[n], 32));
    }
    float den[2] = {0.f, 0.f};
    float at[3][2][4];
#pragma unroll
    for (int m = 0; m < 3; ++m)
#pragma unroll
        for (int n = 0; n < 2; ++n)
#pragma unroll
            for (int reg = 0; reg < 4; ++reg) {
                float e = (tt[m][n][reg] > -1e29f) ? expf(tt[m][n][reg] - mx[n]) : 0.f;
                at[m][n][reg] = e;
                den[n] += e;
            }
#pragma unroll
    for (int n = 0; n < 2; ++n) {
        den[n] += __shfl_xor(den[n], 16);
        den[n] += __shfl_xor(den[n], 32);
    }
    float num[2] = {0.f, 0.f};
#pragma unroll
    for (int m = 0; m < 3; ++m)
#pragma unroll
        for (int n = 0; n < 2; ++n)
#pragma unroll
            for (int reg = 0; reg < 4; ++reg) {
                float a = at[m][n][reg] / den[n];
                at[m][n][reg] = a;
                num[n] += a * acc[m][n][reg];  // attn * raw A0
            }
#pragma unroll
    for (int n = 0; n < 2; ++n) {
        num[n] += __shfl_xor(num[n], 16);
        num[n] += __shfl_xor(num[n], 32);
    }

    // 3) spill attn + num to LDS for the Gram quadratic form
#pragma unroll
    for (int m = 0; m < 3; ++m)
#pragma unroll
        for (int n = 0; n < 2; ++n)
#pragma unroll
            for (int reg = 0; reg < 4; ++reg) {
                int row = m * 16 + grp * 4 + reg;
                if (row < NR) attnS[(wv * NR + row) * 33 + n * 16 + lw] = at[m][n][reg];
            }
    if (grp == 0) {
        numS[wv * NW + lw] = num[0];
        numS[wv * NW + 16 + lw] = num[1];
    }
    __syncthreads();

    // 4) q_w = attn_w^T G attn_w ; lanes: w = l&31, half h = l>>5 covers 18 r' each
    const int w = l & 31, h = l >> 5;
    float a_[NR];
#pragma unroll
    for (int r = 0; r < NR; ++r) a_[r] = attnS[(wv * NR + r) * 33 + w];
    float q = 0.f;
    for (int c = 0; c < 18; ++c) {
        int rp = h * 18 + c;
        float t = 0.f;
#pragma unroll
        for (int r = 0; r < NR; ++r) t += a_[r] * gG[r * NR + rp];
        q += t * attnS[(wv * NR + rp) * 33 + w];
    }
    q += __shfl_xor(q, 32);

    // 5) cosine sim + LSE over 32 words
    if (l < NW) {
        float w2 = sqrtf(fmaxf(q, 0.f));
        float denom = fmaxf(w1g[i * NW + l] * w2, EPSF);
        float sim = numS[wv * NW + l] / denom;
        float m2 = sim;
        for (int off = 16; off; off >>= 1) m2 = fmaxf(m2, __shfl_xor(m2, off));
        float e = expf(LAM_LSE * (sim - m2));
        float ss = e;
        for (int off = 16; off; off >>= 1) ss += __shfl_xor(ss, off);
        if (l == 0) scores[(size_t)j * NI + i] = m2 + logf(ss) / LAM_LSE;
    }
}

// ---------------- final hinge loss over the 128x128 score matrix ----------------
__global__ __launch_bounds__(256) void loss_kernel(const float* __restrict__ scores,
                                                   float* __restrict__ out) {
    __shared__ float diag[NJ];
    __shared__ float part[256];
    const int tid = threadIdx.x;
    if (tid < NJ) diag[tid] = scores[tid * NI + tid];
    __syncthreads();
    float m = 0.f;
    if (tid < 128) {
        const int a = tid;
        const float da = diag[a];
        for (int b = 0; b < NI; ++b) {
            if (b == a) continue;
            float c = MARGIN + scores[a * NI + b] - da;
            m = fmaxf(m, c);
        }
    } else {
        const int b = tid - 128;
        const float db = diag[b];
        for (int a = 0; a < NJ; ++a) {
            if (a == b) continue;
            float c = MARGIN + scores[a * NI + b] - db;
            m = fmaxf(m, c);
        }
    }
    part[tid] = m;
    __syncthreads();
    for (int st = 128; st > 0; st >>= 1) {
        if (tid < st) part[tid] += part[tid + st];
        __syncthreads();
    }
    if (tid == 0) out[0] = part[0];
}

extern "C" void kernel_launch(void* const* d_in, const int* in_sizes, int n_in,
                              void* d_out, int out_size, void* d_ws, size_t ws_size,
                              hipStream_t stream) {
    const float* im = (const float*)d_in[0];
    const float* s = (const float*)d_in[1];

    unsigned short* imh = (unsigned short*)d_ws;
    unsigned short* sh = imh + IM_ELEMS;
    float* G = (float*)(sh + S_ELEMS);
    float* w1 = G + G_SZ;
    float* scores = w1 + W1_SZ;

    cvt_kernel<<<dim3(IM_ELEMS / 4 / 256), dim3(256), 0, stream>>>(im, imh, IM_ELEMS / 4);
    cvt_kernel<<<dim3(S_ELEMS / 4 / 256), dim3(256), 0, stream>>>(s, sh, S_ELEMS / 4);
    gram_kernel<<<dim3(NJ), dim3(256), 0, stream>>>(im, G);
    wnorm_kernel<<<dim3(NI), dim3(256), 0, stream>>>(s, w1);
    mfma_pair_kernel<<<dim3(NI / 8, NJ), dim3(512), 0, stream>>>(imh, sh, G, w1, scores);
    loss_kernel<<<dim3(1), dim3(256), 0, stream>>>(scores, (float*)d_out);
}

// Round 3
// 181.424 us; speedup vs baseline: 9.4287x; 1.3278x over previous
//
#include <hip/hip_runtime.h>

#define NJ 128   // images
#define NI 128   // captions
#define NR 36    // regions
#define NW 32    // words
#define ND 1024  // feature dim

#define LAM_SM 9.0f
#define LAM_LSE 6.0f
#define MARGIN 0.2f
#define EPSF 1e-8f

typedef __attribute__((ext_vector_type(8))) short s16x8;
typedef __attribute__((ext_vector_type(4))) float f32x4;

#define IM_ROWS (NJ * NR)          // 4608
#define S_ROWS  (NI * NW)          // 4096
#define IM_ELEMS (IM_ROWS * ND)
#define S_ELEMS  (S_ROWS * ND)
#define GSW_ELEMS (NJ * 48 * 64)   // bf16, swizzled, zero-padded

__device__ __forceinline__ unsigned short f2bf(float x) {
    unsigned u = __float_as_uint(x);
    return (unsigned short)((u + 0x7FFFu + ((u >> 16) & 1u)) >> 16);
}
__device__ __forceinline__ unsigned pack2bf(float x, float y) {
    return (unsigned)f2bf(x) | ((unsigned)f2bf(y) << 16);
}
__device__ __forceinline__ float bf2f(unsigned short v) {
    return __uint_as_float(((unsigned)v) << 16);
}
__device__ __forceinline__ void gload16(const void* g, void* l) {
    __builtin_amdgcn_global_load_lds((const __attribute__((address_space(1))) unsigned int*)g,
                                     (__attribute__((address_space(3))) unsigned int*)l, 16, 0, 0);
}

// ---- f32 -> bf16 convert + per-64-window chunk XOR swizzle (key = global row & 7) ----
// layout out: [row][window wd(16)][chunk p(8)][elem(8)]; content chunk = p ^ (row&7)
__global__ __launch_bounds__(256) void cvtswz_kernel(const float* __restrict__ src,
                                                     unsigned short* __restrict__ dst) {
    int idx = blockIdx.x * 256 + threadIdx.x;   // chunk id, grid is exact
    int row = idx >> 7, cw = idx & 127;
    int wd = cw >> 3, p = cw & 7;
    int sk = wd * 64 + ((p ^ (row & 7)) * 8);
    const float* sp = src + (size_t)row * 1024 + sk;
    float4 v0 = *(const float4*)sp;
    float4 v1 = *(const float4*)(sp + 4);
    ushort4 o0, o1;
    o0.x = f2bf(v0.x); o0.y = f2bf(v0.y); o0.z = f2bf(v0.z); o0.w = f2bf(v0.w);
    o1.x = f2bf(v1.x); o1.y = f2bf(v1.y); o1.z = f2bf(v1.z); o1.w = f2bf(v1.w);
    ((ushort4*)dst)[idx * 2] = o0;
    ((ushort4*)dst)[idx * 2 + 1] = o1;
}

// ---- word norms w1[i][w] = ||s[i,w,:]|| (f32 exact) ----
__global__ __launch_bounds__(256) void wnorm_kernel(const float* __restrict__ s,
                                                    float* __restrict__ w1) {
    const int i = blockIdx.x;
    const int tid = threadIdx.x;
    const int w = tid >> 3;
    const int part = tid & 7;
    const float* sw = s + ((size_t)i * NW + w) * ND;
    float acc = 0.f;
    for (int k = 0; k < 32; ++k) {
        int c = (part + k * 8) * 4;
        float4 v = *(const float4*)(sw + c);
        acc += v.x * v.x + v.y * v.y + v.z * v.z + v.w * v.w;
    }
    acc += __shfl_xor(acc, 1);
    acc += __shfl_xor(acc, 2);
    acc += __shfl_xor(acc, 4);
    if (part == 0) w1[i * NW + w] = sqrtf(acc);
}

// ---- Gram via MFMA: Gsw[j] = bf16 swizzled 48x64 (rows/cols >=36 zero) ----
__global__ __launch_bounds__(64) void gram_mfma_kernel(const unsigned short* __restrict__ imsw,
                                                       unsigned short* __restrict__ Gsw) {
    const int j = blockIdx.x;
    const int l = threadIdx.x;
    const int grp = l >> 4, lw = l & 15;
    __shared__ __align__(16) char sm[6144 + 48 * 52 * 4];
    float* Gtmp = (float*)(sm + 6144);
    // zero pad rows 36..47 of the staging tile (once)
    {
        int idx = l;
        for (int t = 0; t < 2; ++t, idx += 64) {
            if (idx < 96) {
                int row = 36 + (idx >> 3), p = idx & 7;
                *(int4*)(sm + row * 128 + p * 16) = make_int4(0, 0, 0, 0);
            }
        }
    }
    const int keyadj = (j & 1) * 4;  // (j*36) & 7 == 4*(j&1)
    const char* src = (const char*)imsw + ((size_t)j * 36 + (l >> 3)) * 2048 + (l & 7) * 16;
    f32x4 acc[3][3];
#pragma unroll
    for (int m = 0; m < 3; ++m)
#pragma unroll
        for (int n = 0; n < 3; ++n) acc[m][n] = (f32x4){0.f, 0.f, 0.f, 0.f};

    for (int k0b = 0; k0b < 2048; k0b += 128) {
        asm volatile("s_waitcnt vmcnt(0) lgkmcnt(0)" ::: "memory");
        __syncthreads();
#pragma unroll
        for (int t = 0; t < 5; ++t) {
            if (t < 4 || l < 32) gload16(src + t * 8 * 2048 + k0b, sm + t * 1024);
        }
        asm volatile("s_waitcnt vmcnt(0)" ::: "memory");
        __syncthreads();
#pragma unroll
        for (int ks = 0; ks < 2; ++ks) {
            int swz = (((ks * 4 + grp) ^ ((lw + keyadj) & 7)) << 4);
            s16x8 fr[3];
#pragma unroll
            for (int m = 0; m < 3; ++m)
                fr[m] = *(const s16x8*)(sm + m * 2048 + lw * 128 + swz);
#pragma unroll
            for (int m = 0; m < 3; ++m)
#pragma unroll
                for (int n = 0; n < 3; ++n)
                    acc[m][n] = __builtin_amdgcn_mfma_f32_16x16x32_bf16(fr[m], fr[n], acc[m][n], 0, 0, 0);
        }
    }
#pragma unroll
    for (int m = 0; m < 3; ++m)
#pragma unroll
        for (int n = 0; n < 3; ++n)
#pragma unroll
            for (int reg = 0; reg < 4; ++reg)
                Gtmp[(m * 16 + grp * 4 + reg) * 52 + n * 16 + lw] = acc[m][n][reg];
    asm volatile("s_waitcnt lgkmcnt(0)" ::: "memory");
    __syncthreads();
    // pack to bf16 swizzled (key = local row & 7), cols >= 48 zero
    for (int t = 0; t < 6; ++t) {
        int idx = l + 64 * t;     // 384 chunks
        int row = idx >> 3, p = idx & 7;
        int k0 = (p ^ (row & 7)) * 8;
        ushort4 o0, o1;
        float v[8];
#pragma unroll
        for (int e = 0; e < 8; ++e) {
            int k = k0 + e;
            v[e] = (k < 48) ? Gtmp[row * 52 + k] : 0.f;
        }
        o0.x = f2bf(v[0]); o0.y = f2bf(v[1]); o0.z = f2bf(v[2]); o0.w = f2bf(v[3]);
        o1.x = f2bf(v[4]); o1.y = f2bf(v[5]); o1.z = f2bf(v[6]); o1.w = f2bf(v[7]);
        ushort4* dp = (ushort4*)((char*)Gsw + (size_t)j * 6144 + row * 128 + p * 16);
        dp[0] = o0; dp[1] = o1;
    }
}

// ---- main pair kernel: block = 4 images x 8 captions, 4 waves, wave tile 144x64 ----
__global__ __launch_bounds__(256, 2) void pair2_kernel(const unsigned short* __restrict__ imsw,
                                                       const unsigned short* __restrict__ ssw,
                                                       const unsigned short* __restrict__ Gswp,
                                                       const float* __restrict__ w1g,
                                                       float* __restrict__ scores) {
    const int ig = blockIdx.x;   // caption octet
    const int jg = blockIdx.y;   // image quad
    const int tid = threadIdx.x;
    const int l = tid & 63, wv = tid >> 6;
    const int grp = l >> 4, lw = l & 15;

    // GEMM: sA [0,18432) 144 rows x 128B ; sB [18432,51200) 256 rows x 128B
    // Epi : GswL [0,24576) 4x6144 ; E [24576,57344) 8 caps x (32w x 64rp bf16)
    //       invn [57344,61952) [8 caps][144 rows] f32
    __shared__ __align__(16) char smem[61952];
    char* const EB = smem + 24576;
    char* const NB = smem + 57344;

    const char* imBase = (const char*)imsw + ((size_t)jg * 144 + (l >> 3)) * 2048 + (l & 7) * 16;
    const char* sBase = (const char*)ssw + ((size_t)ig * 256 + wv * 64 + (l >> 3)) * 2048 + (l & 7) * 16;

    f32x4 acc[9][4];
#pragma unroll
    for (int m = 0; m < 9; ++m)
#pragma unroll
        for (int n = 0; n < 4; ++n) acc[m][n] = (f32x4){0.f, 0.f, 0.f, 0.f};

    for (int k0b = 0; k0b < 2048; k0b += 128) {
        __syncthreads();
#pragma unroll
        for (int t = 0; t < 5; ++t) {
            int ii = wv + 4 * t;
            if (ii < 18) gload16(imBase + (size_t)ii * 8 * 2048 + k0b, smem + ii * 1024);
        }
#pragma unroll
        for (int t = 0; t < 8; ++t) {
            gload16(sBase + (size_t)t * 8 * 2048 + k0b, smem + 18432 + wv * 8192 + t * 1024);
        }
        asm volatile("s_waitcnt vmcnt(0)" ::: "memory");
        __syncthreads();
#pragma unroll
        for (int ks = 0; ks < 2; ++ks) {
            const int swz = ((ks * 4 + grp) ^ (lw & 7)) << 4;
            const char* aAddr = smem + lw * 128 + swz;
            const char* bAddr = smem + 18432 + wv * 8192 + lw * 128 + swz;
            s16x8 af[9], bf[4];
#pragma unroll
            for (int m = 0; m < 9; ++m) af[m] = *(const s16x8*)(aAddr + m * 2048);
#pragma unroll
            for (int n = 0; n < 4; ++n) bf[n] = *(const s16x8*)(bAddr + n * 2048);
#pragma unroll
            for (int m = 0; m < 9; ++m)
#pragma unroll
                for (int n = 0; n < 4; ++n)
                    acc[m][n] = __builtin_amdgcn_mfma_f32_16x16x32_bf16(af[m], bf[n], acc[m][n], 0, 0, 0);
        }
    }
    __syncthreads();   // all GEMM LDS reads done; repurpose LDS

    // issue Gsw tiles (4 images) into [0,24576)
    {
        const char* gB = (const char*)Gswp + (size_t)jg * 24576 + l * 16;
#pragma unroll
        for (int t = 0; t < 6; ++t) {
            int ii = wv + 4 * t;
            gload16(gB + ii * 1024, smem + ii * 1024);
        }
    }
    // zero E pads (pairs 18..31 i.e. regions 36..63) for my 2 captions
#pragma unroll
    for (int c = 0; c < 2; ++c) {
        int capL = wv * 2 + c;
        for (int t = 0; t < 7; ++t) {
            int e = l + t * 64;          // 448 = 32w * 14 pairs
            int w = e / 14, pr = e - w * 14 + 18;
            *(unsigned*)(EB + capL * 4096 + w * 128 + (((pr >> 2) ^ (w & 7)) << 4) + (pr & 3) * 4) = 0u;
        }
    }
    // P1: inverse region norms (leaky, over 32 words) -> LDS [cap][row]
#pragma unroll
    for (int m = 0; m < 9; ++m)
#pragma unroll
        for (int reg = 0; reg < 4; ++reg) {
            int row = m * 16 + grp * 4 + reg;
#pragma unroll
            for (int c = 0; c < 2; ++c) {
                float a0 = acc[m][2 * c][reg], a1 = acc[m][2 * c + 1][reg];
                float l0 = a0 > 0.f ? a0 : 0.1f * a0;
                float l1 = a1 > 0.f ? a1 : 0.1f * a1;
                float ss = l0 * l0 + l1 * l1;
                ss += __shfl_xor(ss, 1); ss += __shfl_xor(ss, 2);
                ss += __shfl_xor(ss, 4); ss += __shfl_xor(ss, 8);
                if (lw == 0)
                    *(float*)(NB + ((wv * 2 + c) * 144 + row) * 4) = 1.f / (sqrtf(ss) + EPSF);
            }
        }
    // P2: per-image per-word max logit
    float mx[4][4];
#pragma unroll
    for (int a = 0; a < 4; ++a)
#pragma unroll
        for (int b = 0; b < 4; ++b) mx[a][b] = -1e30f;
#pragma unroll
    for (int m = 0; m < 9; ++m) {
        int rbase = m * 16 + grp * 4;
        int img = (rbase * 1821) >> 16;   // rbase / 36
#pragma unroll
        for (int c = 0; c < 2; ++c) {
            float iv[4];
#pragma unroll
            for (int reg = 0; reg < 4; ++reg)
                iv[reg] = *(const float*)(NB + ((wv * 2 + c) * 144 + rbase + reg) * 4);
#pragma unroll
            for (int nn = 0; nn < 2; ++nn) {
                int n = c * 2 + nn;
                float t4 = -1e30f;
#pragma unroll
                for (int reg = 0; reg < 4; ++reg) {
                    float a = acc[m][n][reg];
                    float lk = a > 0.f ? a : 0.1f * a;
                    t4 = fmaxf(t4, LAM_SM * lk * iv[reg]);
                }
#pragma unroll
                for (int mm = 0; mm < 4; ++mm)
                    mx[mm][n] = (img == mm) ? fmaxf(mx[mm][n], t4) : mx[mm][n];
            }
        }
    }
#pragma unroll
    for (int a = 0; a < 4; ++a)
#pragma unroll
        for (int b = 0; b < 4; ++b) {
            mx[a][b] = fmaxf(mx[a][b], __shfl_xor(mx[a][b], 16));
            mx[a][b] = fmaxf(mx[a][b], __shfl_xor(mx[a][b], 32));
        }

    float w1v[4];
#pragma unroll
    for (int n = 0; n < 4; ++n) {
        int capG = ig * 8 + wv * 2 + (n >> 1);
        int w = (n & 1) * 16 + lw;
        w1v[n] = w1g[capG * 32 + w];
    }

    asm volatile("s_waitcnt vmcnt(0)" ::: "memory");
    __syncthreads();   // Gsw tiles ready

#pragma unroll
    for (int IMG = 0; IMG < 4; ++IMG) {
        float dn[4] = {0.f, 0.f, 0.f, 0.f}, nm[4] = {0.f, 0.f, 0.f, 0.f};
        // P3: e = exp(t - mx), accumulate den/num, write E (bf16) for this image
#pragma unroll
        for (int m = 0; m < 9; ++m) {
            int rbase = m * 16 + grp * 4;
            int img = (rbase * 1821) >> 16;
            bool pred = (img == IMG);
            int rp0 = rbase - IMG * 36;
#pragma unroll
            for (int c = 0; c < 2; ++c) {
                float iv[4];
#pragma unroll
                for (int reg = 0; reg < 4; ++reg)
                    iv[reg] = *(const float*)(NB + ((wv * 2 + c) * 144 + rbase + reg) * 4);
#pragma unroll
                for (int nn = 0; nn < 2; ++nn) {
                    int n = c * 2 + nn;
                    int w = nn * 16 + lw;
                    float e[4];
#pragma unroll
                    for (int reg = 0; reg < 4; ++reg) {
                        float a = acc[m][n][reg];
                        float lk = a > 0.f ? a : 0.1f * a;
                        float t = LAM_SM * lk * iv[reg];
                        e[reg] = pred ? __expf(t - mx[IMG][n]) : 0.f;
                        dn[n] += e[reg];
                        nm[n] += e[reg] * a;
                    }
                    if (pred) {
                        int ch = rp0 >> 3;
                        char* base = EB + (wv * 2 + c) * 4096 + w * 128 + ((ch ^ (w & 7)) << 4) + (rp0 & 7) * 2;
                        *(unsigned*)(base) = pack2bf(e[0], e[1]);
                        *(unsigned*)(base + 4) = pack2bf(e[2], e[3]);
                    }
                }
            }
        }
#pragma unroll
        for (int n = 0; n < 4; ++n) {
            dn[n] += __shfl_xor(dn[n], 16); dn[n] += __shfl_xor(dn[n], 32);
            nm[n] += __shfl_xor(nm[n], 16); nm[n] += __shfl_xor(nm[n], 32);
        }
        // P4: U = Gsw[IMG] x E ; q = sum E .* U
        f32x4 u[3][4];
#pragma unroll
        for (int m = 0; m < 3; ++m)
#pragma unroll
            for (int n = 0; n < 4; ++n) u[m][n] = (f32x4){0.f, 0.f, 0.f, 0.f};
#pragma unroll
        for (int ks = 0; ks < 2; ++ks) {
            int swz = ((ks * 4 + grp) ^ (lw & 7)) << 4;
            s16x8 ga[3], eb[4];
#pragma unroll
            for (int m = 0; m < 3; ++m)
                ga[m] = *(const s16x8*)(smem + IMG * 6144 + m * 2048 + lw * 128 + swz);
#pragma unroll
            for (int n = 0; n < 4; ++n) {
                int w = (n & 1) * 16 + lw;
                int capL = wv * 2 + (n >> 1);
                eb[n] = *(const s16x8*)(EB + capL * 4096 + w * 128 + (((ks * 4 + grp) ^ (w & 7)) << 4));
            }
#pragma unroll
            for (int m = 0; m < 3; ++m)
#pragma unroll
                for (int n = 0; n < 4; ++n)
                    u[m][n] = __builtin_amdgcn_mfma_f32_16x16x32_bf16(ga[m], eb[n], u[m][n], 0, 0, 0);
        }
        float qq[4] = {0.f, 0.f, 0.f, 0.f};
#pragma unroll
        for (int m = 0; m < 3; ++m)
#pragma unroll
            for (int n = 0; n < 4; ++n) {
                int w = (n & 1) * 16 + lw;
                int capL = wv * 2 + (n >> 1);
#pragma unroll
                for (int reg = 0; reg < 4; ++reg) {
                    int rp = m * 16 + grp * 4 + reg;
                    unsigned short ev = *(const unsigned short*)(EB + capL * 4096 + w * 128 +
                                                                (((rp >> 3) ^ (w & 7)) << 4) + (rp & 7) * 2);
                    qq[n] += u[m][n][reg] * bf2f(ev);
                }
            }
#pragma unroll
        for (int n = 0; n < 4; ++n) { qq[n] += __shfl_xor(qq[n], 16); qq[n] += __shfl_xor(qq[n], 32); }
        // P5: cosine sim + LSE over 32 words -> score
        float sim[4];
#pragma unroll
        for (int n = 0; n < 4; ++n)
            sim[n] = nm[n] / fmaxf(w1v[n] * sqrtf(fmaxf(qq[n], 0.f)), EPSF * dn[n]);
#pragma unroll
        for (int c2 = 0; c2 < 2; ++c2) {
            float s0 = sim[c2 * 2], s1 = sim[c2 * 2 + 1];
            float m2 = fmaxf(s0, s1);
            m2 = fmaxf(m2, __shfl_xor(m2, 1)); m2 = fmaxf(m2, __shfl_xor(m2, 2));
            m2 = fmaxf(m2, __shfl_xor(m2, 4)); m2 = fmaxf(m2, __shfl_xor(m2, 8));
            float ssum = __expf(LAM_LSE * (s0 - m2)) + __expf(LAM_LSE * (s1 - m2));
            ssum += __shfl_xor(ssum, 1); ssum += __shfl_xor(ssum, 2);
            ssum += __shfl_xor(ssum, 4); ssum += __shfl_xor(ssum, 8);
            if (l == 0)
                scores[(size_t)(jg * 4 + IMG) * NI + ig * 8 + wv * 2 + c2] = m2 + logf(ssum) / LAM_LSE;
        }
    }
}

// ---- final hinge loss over the 128x128 score matrix ----
__global__ __launch_bounds__(256) void loss_kernel(const float* __restrict__ scores,
                                                   float* __restrict__ out) {
    __shared__ float diag[NJ];
    __shared__ float part[256];
    const int tid = threadIdx.x;
    if (tid < NJ) diag[tid] = scores[tid * NI + tid];
    __syncthreads();
    float m = 0.f;
    if (tid < 128) {
        const int a = tid;
        const float da = diag[a];
        for (int b = 0; b < NI; ++b) {
            if (b == a) continue;
            float c = MARGIN + scores[a * NI + b] - da;
            m = fmaxf(m, c);
        }
    } else {
        const int b = tid - 128;
        const float db = diag[b];
        for (int a = 0; a < NJ; ++a) {
            if (a == b) continue;
            float c = MARGIN + scores[a * NI + b] - db;
            m = fmaxf(m, c);
        }
    }
    part[tid] = m;
    __syncthreads();
    for (int st = 128; st > 0; st >>= 1) {
        if (tid < st) part[tid] += part[tid + st];
        __syncthreads();
    }
    if (tid == 0) out[0] = part[0];
}

extern "C" void kernel_launch(void* const* d_in, const int* in_sizes, int n_in,
                              void* d_out, int out_size, void* d_ws, size_t ws_size,
                              hipStream_t stream) {
    const float* im = (const float*)d_in[0];
    const float* s = (const float*)d_in[1];

    unsigned short* imsw = (unsigned short*)d_ws;
    unsigned short* ssw = imsw + IM_ELEMS;
    unsigned short* Gswp = ssw + S_ELEMS;
    float* w1 = (float*)(Gswp + GSW_ELEMS);
    float* scores = w1 + S_ROWS;

    cvtswz_kernel<<<dim3(IM_ROWS * 128 / 256), dim3(256), 0, stream>>>(im, imsw);
    cvtswz_kernel<<<dim3(S_ROWS * 128 / 256), dim3(256), 0, stream>>>(s, ssw);
    wnorm_kernel<<<dim3(NI), dim3(256), 0, stream>>>(s, w1);
    gram_mfma_kernel<<<dim3(NJ), dim3(64), 0, stream>>>(imsw, Gswp);
    pair2_kernel<<<dim3(NI / 8, NJ / 4), dim3(256), 0, stream>>>(imsw, ssw, Gswp, w1, scores);
    loss_kernel<<<dim3(1), dim3(256), 0, stream>>>(scores, (float*)d_out);
}

// Round 4
// 170.057 us; speedup vs baseline: 10.0590x; 1.0668x over previous
//
#include <hip/hip_runtime.h>

#define NJ 128   // images
#define NI 128   // captions
#define NR 36    // regions
#define NW 32    // words
#define ND 1024  // feature dim

#define LAM_SM 9.0f
#define LAM_LSE 6.0f
#define MARGIN 0.2f
#define EPSF 1e-8f

typedef __attribute__((ext_vector_type(8))) short s16x8;
typedef __attribute__((ext_vector_type(4))) float f32x4;

#define IM_ROWS (NJ * NR)          // 4608
#define S_ROWS  (NI * NW)          // 4096
#define IM_ELEMS (IM_ROWS * ND)
#define S_ELEMS  (S_ROWS * ND)
#define GSW_ELEMS (NJ * 48 * 64)   // bf16, swizzled, zero-padded

// pair3 LDS map (dynamic, 139264 B):
//   buf0 [0,69632): A 288x128B [0,36864) + B 256x128B [36864,69632)
//   buf1 [69632,139264): same
//   epilogue overlay: Gd 8x6144 [0,49152) | E 16 slots x 4096 [49152,114688)
//                     | NB f32 [8 caps][288] [114688,123904)
#define BUFSZ 69632
#define E_OFF 49152
#define NB_OFF 114688
#define SMEM_TOTAL 139264

__device__ __forceinline__ float dot4(float4 a, float4 b) {
    return a.x * b.x + a.y * b.y + a.z * b.z + a.w * b.w;
}
__device__ __forceinline__ unsigned short f2bf(float x) {
    unsigned u = __float_as_uint(x);
    return (unsigned short)((u + 0x7FFFu + ((u >> 16) & 1u)) >> 16);
}
__device__ __forceinline__ unsigned pack2bf(float x, float y) {
    return (unsigned)f2bf(x) | ((unsigned)f2bf(y) << 16);
}
__device__ __forceinline__ float bf2f(unsigned v) {
    return __uint_as_float((v & 0xffffu) << 16);
}
__device__ __forceinline__ void gload16(const void* g, void* l) {
    __builtin_amdgcn_global_load_lds((const __attribute__((address_space(1))) unsigned int*)g,
                                     (__attribute__((address_space(3))) unsigned int*)l, 16, 0, 0);
}

// ---- f32 -> bf16 convert + per-64-window chunk XOR swizzle (key = global row & 7) ----
__global__ __launch_bounds__(256) void cvtswz_kernel(const float* __restrict__ src,
                                                     unsigned short* __restrict__ dst) {
    int idx = blockIdx.x * 256 + threadIdx.x;
    int row = idx >> 7, cw = idx & 127;
    int wd = cw >> 3, p = cw & 7;
    int sk = wd * 64 + ((p ^ (row & 7)) * 8);
    const float* sp = src + (size_t)row * 1024 + sk;
    float4 v0 = *(const float4*)sp;
    float4 v1 = *(const float4*)(sp + 4);
    ushort4 o0, o1;
    o0.x = f2bf(v0.x); o0.y = f2bf(v0.y); o0.z = f2bf(v0.z); o0.w = f2bf(v0.w);
    o1.x = f2bf(v1.x); o1.y = f2bf(v1.y); o1.z = f2bf(v1.z); o1.w = f2bf(v1.w);
    ((ushort4*)dst)[idx * 2] = o0;
    ((ushort4*)dst)[idx * 2 + 1] = o1;
}

// ---- word norms w1[i][w] = ||s[i,w,:]|| (f32 exact) ----
__global__ __launch_bounds__(256) void wnorm_kernel(const float* __restrict__ s,
                                                    float* __restrict__ w1) {
    const int i = blockIdx.x;
    const int tid = threadIdx.x;
    const int w = tid >> 3;
    const int part = tid & 7;
    const float* sw = s + ((size_t)i * NW + w) * ND;
    float acc = 0.f;
    for (int k = 0; k < 32; ++k) {
        int c = (part + k * 8) * 4;
        float4 v = *(const float4*)(sw + c);
        acc += v.x * v.x + v.y * v.y + v.z * v.z + v.w * v.w;
    }
    acc += __shfl_xor(acc, 1);
    acc += __shfl_xor(acc, 2);
    acc += __shfl_xor(acc, 4);
    if (part == 0) w1[i * NW + w] = sqrtf(acc);
}

// ---- Gram via MFMA: Gsw[j] = bf16 swizzled 48x64 (rows/cols >=36 zero) ----
__global__ __launch_bounds__(64) void gram_mfma_kernel(const unsigned short* __restrict__ imsw,
                                                       unsigned short* __restrict__ Gsw) {
    const int j = blockIdx.x;
    const int l = threadIdx.x;
    const int grp = l >> 4, lw = l & 15;
    __shared__ __align__(16) char sm[6144 + 48 * 52 * 4];
    float* Gtmp = (float*)(sm + 6144);
    {
        int idx = l;
        for (int t = 0; t < 2; ++t, idx += 64) {
            if (idx < 96) {
                int row = 36 + (idx >> 3), p = idx & 7;
                *(int4*)(sm + row * 128 + p * 16) = make_int4(0, 0, 0, 0);
            }
        }
    }
    const int keyadj = (j & 1) * 4;
    const char* src = (const char*)imsw + ((size_t)j * 36 + (l >> 3)) * 2048 + (l & 7) * 16;
    f32x4 acc[3][3];
#pragma unroll
    for (int m = 0; m < 3; ++m)
#pragma unroll
        for (int n = 0; n < 3; ++n) acc[m][n] = (f32x4){0.f, 0.f, 0.f, 0.f};

    for (int k0b = 0; k0b < 2048; k0b += 128) {
        asm volatile("s_waitcnt vmcnt(0) lgkmcnt(0)" ::: "memory");
        __syncthreads();
#pragma unroll
        for (int t = 0; t < 5; ++t) {
            if (t < 4 || l < 32) gload16(src + t * 8 * 2048 + k0b, sm + t * 1024);
        }
        asm volatile("s_waitcnt vmcnt(0)" ::: "memory");
        __syncthreads();
#pragma unroll
        for (int ks = 0; ks < 2; ++ks) {
            int swz = (((ks * 4 + grp) ^ ((lw + keyadj) & 7)) << 4);
            s16x8 fr[3];
#pragma unroll
            for (int m = 0; m < 3; ++m)
                fr[m] = *(const s16x8*)(sm + m * 2048 + lw * 128 + swz);
#pragma unroll
            for (int m = 0; m < 3; ++m)
#pragma unroll
                for (int n = 0; n < 3; ++n)
                    acc[m][n] = __builtin_amdgcn_mfma_f32_16x16x32_bf16(fr[m], fr[n], acc[m][n], 0, 0, 0);
        }
    }
#pragma unroll
    for (int m = 0; m < 3; ++m)
#pragma unroll
        for (int n = 0; n < 3; ++n)
#pragma unroll
            for (int reg = 0; reg < 4; ++reg)
                Gtmp[(m * 16 + grp * 4 + reg) * 52 + n * 16 + lw] = acc[m][n][reg];
    asm volatile("s_waitcnt lgkmcnt(0)" ::: "memory");
    __syncthreads();
    for (int t = 0; t < 6; ++t) {
        int idx = l + 64 * t;
        int row = idx >> 3, p = idx & 7;
        int k0 = (p ^ (row & 7)) * 8;
        ushort4 o0, o1;
        float v[8];
#pragma unroll
        for (int e = 0; e < 8; ++e) {
            int k = k0 + e;
            v[e] = (k < 48) ? Gtmp[row * 52 + k] : 0.f;
        }
        o0.x = f2bf(v[0]); o0.y = f2bf(v[1]); o0.z = f2bf(v[2]); o0.w = f2bf(v[3]);
        o1.x = f2bf(v[4]); o1.y = f2bf(v[5]); o1.z = f2bf(v[6]); o1.w = f2bf(v[7]);
        ushort4* dp = (ushort4*)((char*)Gsw + (size_t)j * 6144 + row * 128 + p * 16);
        dp[0] = o0; dp[1] = o1;
    }
}

// ---- main pair kernel: block = 8 images x 8 captions, 8 waves (2M x 4N) ----
__global__ __launch_bounds__(512, 2) void pair3_kernel(const unsigned short* __restrict__ imsw,
                                                       const unsigned short* __restrict__ ssw,
                                                       const unsigned short* __restrict__ Gswp,
                                                       const float* __restrict__ w1g,
                                                       float* __restrict__ scores) {
    extern __shared__ char smem[];
    const int ig = blockIdx.x;   // caption octet
    const int jg = blockIdx.y;   // image octet
    const int tid = threadIdx.x;
    const int l = tid & 63, wv = tid >> 6;
    const int grp = l >> 4, lw = l & 15;
    const int wm = wv >> 2, wn = wv & 3;

    const char* aSrc = (const char*)imsw + ((size_t)(jg * 288) + (l >> 3)) * 2048 + (l & 7) * 16;
    const char* bSrc = (const char*)ssw + ((size_t)(ig * 256) + (l >> 3)) * 2048 + (l & 7) * 16;

    f32x4 acc[9][4];
#pragma unroll
    for (int m = 0; m < 9; ++m)
#pragma unroll
        for (int n = 0; n < 4; ++n) acc[m][n] = (f32x4){0.f, 0.f, 0.f, 0.f};

    auto stage = [&](int bb, int k0b) {
        char* ab = smem + bb;
#pragma unroll
        for (int t = 0; t < 5; ++t) {
            int ii = wv + 8 * t;
            if (ii < 36) gload16(aSrc + (size_t)ii * 16384 + k0b, ab + ii * 1024);
        }
        char* bbp = smem + bb + 36864;
#pragma unroll
        for (int t = 0; t < 4; ++t) {
            int ii = wv + 8 * t;
            gload16(bSrc + (size_t)ii * 16384 + k0b, bbp + ii * 1024);
        }
    };
    auto compute = [&](int bb) {
        const char* A = smem + bb;
        const char* B = smem + bb + 36864;
#pragma unroll
        for (int ks = 0; ks < 2; ++ks) {
            const int swz = (((ks * 4 + grp) ^ (lw & 7)) << 4);
            s16x8 af[9], bf[4];
#pragma unroll
            for (int m = 0; m < 9; ++m)
                af[m] = *(const s16x8*)(A + (wm * 144 + m * 16 + lw) * 128 + swz);
#pragma unroll
            for (int n = 0; n < 4; ++n)
                bf[n] = *(const s16x8*)(B + (wn * 64 + n * 16 + lw) * 128 + swz);
#pragma unroll
            for (int m = 0; m < 9; ++m)
#pragma unroll
                for (int n = 0; n < 4; ++n)
                    acc[m][n] = __builtin_amdgcn_mfma_f32_16x16x32_bf16(af[m], bf[n], acc[m][n], 0, 0, 0);
        }
    };

    stage(0, 0);
    asm volatile("s_waitcnt vmcnt(0)" ::: "memory");
    __syncthreads();
    for (int t = 0; t < 16; ++t) {
        if (t < 15) {
            stage(((t + 1) & 1) * BUFSZ, (t + 1) * 128);
        } else {
            // prefetch Gram tiles for the 8 images into dead buf0
            const char* gB = (const char*)Gswp + (size_t)jg * 49152 + l * 16;
#pragma unroll
            for (int u = 0; u < 6; ++u) {
                int ii = wv + 8 * u;
                gload16(gB + (size_t)ii * 1024, smem + ii * 1024);
            }
        }
        compute((t & 1) * BUFSZ);
        asm volatile("s_waitcnt vmcnt(0)" ::: "memory");
        __syncthreads();
    }

    // ================= barrier-free per-wave epilogue =================
    // wave (wm,wn): rows wm*144..+144 (images wm*4..+4), caps wn*2, wn*2+1
    char* myE[2];
    myE[0] = smem + E_OFF + (wm * 8 + wn * 2) * 4096;
    myE[1] = myE[0] + 4096;
    float* NB = (float*)(smem + NB_OFF);

    // zero E pads (regions 36..63) for my 2 slots
#pragma unroll
    for (int c = 0; c < 2; ++c) {
        char* Eb = myE[c];
#pragma unroll
        for (int u = 0; u < 7; ++u) {
            int e = l + u * 64;               // 448 = 32w * 14 pairs
            int w = e / 14, pr = e - w * 14 + 18;
            *(unsigned*)(Eb + w * 128 + (((pr >> 2) ^ (w & 7)) << 4) + (pr & 3) * 4) = 0u;
        }
    }

    // P1: inverse region norms (leaky, over 32 words) -> NB[cap][288]
#pragma unroll
    for (int m = 0; m < 9; ++m)
#pragma unroll
        for (int reg = 0; reg < 4; ++reg) {
            int rowL = m * 16 + grp * 4 + reg;
#pragma unroll
            for (int c = 0; c < 2; ++c) {
                float a0 = acc[m][2 * c][reg], a1 = acc[m][2 * c + 1][reg];
                float l0 = a0 > 0.f ? a0 : 0.1f * a0;
                float l1 = a1 > 0.f ? a1 : 0.1f * a1;
                float ss = l0 * l0 + l1 * l1;
                ss += __shfl_xor(ss, 1); ss += __shfl_xor(ss, 2);
                ss += __shfl_xor(ss, 4); ss += __shfl_xor(ss, 8);
                if (lw == 0)
                    NB[(wn * 2 + c) * 288 + wm * 144 + rowL] = 1.f / (sqrtf(ss) + EPSF);
            }
        }

    // P2: per-local-image per-word max logit
    float mx[4][4];
#pragma unroll
    for (int a = 0; a < 4; ++a)
#pragma unroll
        for (int b = 0; b < 4; ++b) mx[a][b] = -1e30f;
#pragma unroll
    for (int m = 0; m < 9; ++m) {
        int rbase = m * 16 + grp * 4;
        int img = (rbase * 1821) >> 16;      // rbase / 36
#pragma unroll
        for (int c = 0; c < 2; ++c) {
            float4 iv = *(const float4*)&NB[(wn * 2 + c) * 288 + wm * 144 + rbase];
            float ivr[4] = {iv.x, iv.y, iv.z, iv.w};
#pragma unroll
            for (int nn = 0; nn < 2; ++nn) {
                int n = c * 2 + nn;
                float t4 = -1e30f;
#pragma unroll
                for (int reg = 0; reg < 4; ++reg) {
                    float a = acc[m][n][reg];
                    float lk = a > 0.f ? a : 0.1f * a;
                    t4 = fmaxf(t4, LAM_SM * lk * ivr[reg]);
                }
#pragma unroll
                for (int mm = 0; mm < 4; ++mm)
                    mx[mm][n] = (img == mm) ? fmaxf(mx[mm][n], t4) : mx[mm][n];
            }
        }
    }
#pragma unroll
    for (int a = 0; a < 4; ++a)
#pragma unroll
        for (int b = 0; b < 4; ++b) {
            mx[a][b] = fmaxf(mx[a][b], __shfl_xor(mx[a][b], 16));
            mx[a][b] = fmaxf(mx[a][b], __shfl_xor(mx[a][b], 32));
        }

    float w1v[4];
#pragma unroll
    for (int n = 0; n < 4; ++n)
        w1v[n] = w1g[(ig * 8 + wn * 2 + (n >> 1)) * 32 + (n & 1) * 16 + lw];

#pragma unroll
    for (int L = 0; L < 4; ++L) {
        const int mlo = (L * 36) >> 4, mhi = (L * 36 + 35) >> 4;
        float dn[4] = {0.f, 0.f, 0.f, 0.f}, nm[4] = {0.f, 0.f, 0.f, 0.f};
        // P3: e = exp(t - mx), accumulate den/num, write E (bf16)
#pragma unroll
        for (int m = mlo; m <= mhi; ++m) {
            int rbase = m * 16 + grp * 4;
            int img = (rbase * 1821) >> 16;
            bool pred = (img == L);
            int rp0 = rbase - L * 36;
#pragma unroll
            for (int c = 0; c < 2; ++c) {
                float4 iv = *(const float4*)&NB[(wn * 2 + c) * 288 + wm * 144 + rbase];
                float ivr[4] = {iv.x, iv.y, iv.z, iv.w};
#pragma unroll
                for (int nn = 0; nn < 2; ++nn) {
                    int n = c * 2 + nn;
                    int w = nn * 16 + lw;
                    float e[4];
#pragma unroll
                    for (int reg = 0; reg < 4; ++reg) {
                        float a = acc[m][n][reg];
                        float lk = a > 0.f ? a : 0.1f * a;
                        float tl = LAM_SM * lk * ivr[reg];
                        e[reg] = pred ? __expf(tl - mx[L][n]) : 0.f;
                        dn[n] += e[reg];
                        nm[n] += e[reg] * a;
                    }
                    if (pred) {
                        char* base = myE[c] + w * 128 + (((rp0 >> 3) ^ (w & 7)) << 4) + (rp0 & 7) * 2;
                        *(unsigned*)(base) = pack2bf(e[0], e[1]);
                        *(unsigned*)(base + 4) = pack2bf(e[2], e[3]);
                    }
                }
            }
        }
#pragma unroll
        for (int n = 0; n < 4; ++n) {
            dn[n] += __shfl_xor(dn[n], 16); dn[n] += __shfl_xor(dn[n], 32);
            nm[n] += __shfl_xor(nm[n], 16); nm[n] += __shfl_xor(nm[n], 32);
        }
        // P4: U = Gd[img] x E ; q = sum E .* U
        const char* Gd = smem + (wm * 4 + L) * 6144;
        f32x4 u[3][4];
#pragma unroll
        for (int m = 0; m < 3; ++m)
#pragma unroll
            for (int n = 0; n < 4; ++n) u[m][n] = (f32x4){0.f, 0.f, 0.f, 0.f};
#pragma unroll
        for (int ks = 0; ks < 2; ++ks) {
            int swz = (((ks * 4 + grp) ^ (lw & 7)) << 4);
            s16x8 ga[3], eb[4];
#pragma unroll
            for (int m = 0; m < 3; ++m)
                ga[m] = *(const s16x8*)(Gd + (m * 16 + lw) * 128 + swz);
#pragma unroll
            for (int n = 0; n < 4; ++n) {
                int w = (n & 1) * 16 + lw;
                eb[n] = *(const s16x8*)(myE[n >> 1] + w * 128 + (((ks * 4 + grp) ^ (w & 7)) << 4));
            }
#pragma unroll
            for (int m = 0; m < 3; ++m)
#pragma unroll
                for (int n = 0; n < 4; ++n)
                    u[m][n] = __builtin_amdgcn_mfma_f32_16x16x32_bf16(ga[m], eb[n], u[m][n], 0, 0, 0);
        }
        float qq[4] = {0.f, 0.f, 0.f, 0.f};
#pragma unroll
        for (int m = 0; m < 3; ++m)
#pragma unroll
            for (int n = 0; n < 4; ++n) {
                int w = (n & 1) * 16 + lw;
                const char* base = myE[n >> 1] + w * 128;
#pragma unroll
                for (int rg = 0; rg < 4; rg += 2) {
                    int rp = m * 16 + grp * 4 + rg;
                    unsigned pv = *(const unsigned*)(base + (((rp >> 3) ^ (w & 7)) << 4) + (rp & 7) * 2);
                    qq[n] += u[m][n][rg] * bf2f(pv) + u[m][n][rg + 1] * bf2f(pv >> 16);
                }
            }
#pragma unroll
        for (int n = 0; n < 4; ++n) {
            qq[n] += __shfl_xor(qq[n], 16); qq[n] += __shfl_xor(qq[n], 32);
        }
        // P5: cosine sim + LSE over 32 words -> score
        float sim[4];
#pragma unroll
        for (int n = 0; n < 4; ++n)
            sim[n] = nm[n] / fmaxf(w1v[n] * sqrtf(fmaxf(qq[n], 0.f)), EPSF * dn[n]);
#pragma unroll
        for (int c2 = 0; c2 < 2; ++c2) {
            float s0 = sim[c2 * 2], s1 = sim[c2 * 2 + 1];
            float m2 = fmaxf(s0, s1);
            m2 = fmaxf(m2, __shfl_xor(m2, 1)); m2 = fmaxf(m2, __shfl_xor(m2, 2));
            m2 = fmaxf(m2, __shfl_xor(m2, 4)); m2 = fmaxf(m2, __shfl_xor(m2, 8));
            float ssum = __expf(LAM_LSE * (s0 - m2)) + __expf(LAM_LSE * (s1 - m2));
            ssum += __shfl_xor(ssum, 1); ssum += __shfl_xor(ssum, 2);
            ssum += __shfl_xor(ssum, 4); ssum += __shfl_xor(ssum, 8);
            if (l == 0)
                scores[(size_t)(jg * 8 + wm * 4 + L) * NI + ig * 8 + wn * 2 + c2] =
                    m2 + logf(ssum) / LAM_LSE;
        }
    }
}

// ---- final hinge loss over the 128x128 score matrix ----
__global__ __launch_bounds__(256) void loss_kernel(const float* __restrict__ scores,
                                                   float* __restrict__ out) {
    __shared__ float diag[NJ];
    __shared__ float part[256];
    const int tid = threadIdx.x;
    if (tid < NJ) diag[tid] = scores[tid * NI + tid];
    __syncthreads();
    float m = 0.f;
    if (tid < 128) {
        const int a = tid;
        const float da = diag[a];
        for (int b = 0; b < NI; ++b) {
            if (b == a) continue;
            float c = MARGIN + scores[a * NI + b] - da;
            m = fmaxf(m, c);
        }
    } else {
        const int b = tid - 128;
        const float db = diag[b];
        for (int a = 0; a < NJ; ++a) {
            if (a == b) continue;
            float c = MARGIN + scores[a * NI + b] - db;
            m = fmaxf(m, c);
        }
    }
    part[tid] = m;
    __syncthreads();
    for (int st = 128; st > 0; st >>= 1) {
        if (tid < st) part[tid] += part[tid + st];
        __syncthreads();
    }
    if (tid == 0) out[0] = part[0];
}

extern "C" void kernel_launch(void* const* d_in, const int* in_sizes, int n_in,
                              void* d_out, int out_size, void* d_ws, size_t ws_size,
                              hipStream_t stream) {
    const float* im = (const float*)d_in[0];
    const float* s = (const float*)d_in[1];

    unsigned short* imsw = (unsigned short*)d_ws;
    unsigned short* ssw = imsw + IM_ELEMS;
    unsigned short* Gswp = ssw + S_ELEMS;
    float* w1 = (float*)(Gswp + GSW_ELEMS);
    float* scores = w1 + S_ROWS;

    hipFuncSetAttribute((const void*)pair3_kernel,
                        hipFuncAttributeMaxDynamicSharedMemorySize, SMEM_TOTAL);

    cvtswz_kernel<<<dim3(IM_ROWS * 128 / 256), dim3(256), 0, stream>>>(im, imsw);
    cvtswz_kernel<<<dim3(S_ROWS * 128 / 256), dim3(256), 0, stream>>>(s, ssw);
    wnorm_kernel<<<dim3(NI), dim3(256), 0, stream>>>(s, w1);
    gram_mfma_kernel<<<dim3(NJ), dim3(64), 0, stream>>>(imsw, Gswp);
    pair3_kernel<<<dim3(NI / 8, NJ / 8), dim3(512), SMEM_TOTAL, stream>>>(imsw, ssw, Gswp, w1, scores);
    loss_kernel<<<dim3(1), dim3(256), 0, stream>>>(scores, (float*)d_out);
}